// Round 9
// baseline (537.231 us; speedup 1.0000x reference)
//
#include <hip/hip_runtime.h>
#include <math.h>

static constexpr int D = 64;     // hidden dim
static constexpr int F = 128;    // input features
static constexpr float NEG_SLOPE = 0.2f;
static constexpr float LN_EPS = 1e-5f;
static constexpr float LOG2E = 1.44269504088896340736f;
static constexpr int SCAN_B = 1024;  // elements per scan block (256 thr x 4)
static constexpr int NCHUNK = 8;     // dst-range chunks (== NXCD)

// ---- DPP cross-lane reduction helpers (no LDS traffic) ----
template <int CTRL>
__device__ __forceinline__ float dpp_add(float x) {
  int v = __builtin_amdgcn_update_dpp(0, __float_as_int(x), CTRL, 0xF, 0xF, true);
  return x + __int_as_float(v);
}
// sum within each aligned 16-lane group (result replicated in all 16 lanes)
__device__ __forceinline__ float red16(float x) {
  x = dpp_add<0xB1>(x);    // quad_perm [1,0,3,2]  (xor 1)
  x = dpp_add<0x4E>(x);    // quad_perm [2,3,0,1]  (xor 2)
  x = dpp_add<0x141>(x);   // row_half_mirror
  x = dpp_add<0x140>(x);   // row_mirror
  return x;
}
// sum across full 64-lane wave
__device__ __forceinline__ float red64(float x) {
  x = red16(x);
  x += __shfl_xor(x, 16);
  x += __shfl_xor(x, 32);
  return x;
}

// ---------------- CSR build ----------------

__global__ __launch_bounds__(256) void k_init_cnt(int* __restrict__ cnt, int N) {
  int i = blockIdx.x * 256 + threadIdx.x;
  if (i < N) cnt[i] = 1;  // self-loop
}

// dst-range partitioned histogram: chunk c = blockIdx%8 -> XCD-local atomics.
__global__ __launch_bounds__(256) void k_hist(const int* __restrict__ dst,
                                              int* __restrict__ cnt, int E, int N) {
  int c = blockIdx.x & (NCHUNK - 1);
  int b0 = (c * N) / NCHUNK, b1 = ((c + 1) * N) / NCHUNK;
  int stride = (gridDim.x / NCHUNK) * 256;
  for (int e = (blockIdx.x >> 3) * 256 + threadIdx.x; e < E; e += stride) {
    int d = dst[e];
    if (d >= b0 && d < b1) atomicAdd(&cnt[d], 1);
  }
}

// Stage A: per-block local exclusive scan (4 elems/thread) + block sum.
__global__ __launch_bounds__(256) void k_scan_local(const int* __restrict__ cnt,
                                                    int* __restrict__ row_ptr,
                                                    int* __restrict__ bsum, int N) {
  __shared__ int ts[256];
  int t = threadIdx.x;
  int base = blockIdx.x * SCAN_B + t * 4;
  int v[4];
  int s = 0;
#pragma unroll
  for (int i = 0; i < 4; ++i) {
    int idx = base + i;
    v[i] = (idx < N) ? cnt[idx] : 0;
    s += v[i];
  }
  ts[t] = s;
  __syncthreads();
#pragma unroll
  for (int off = 1; off < 256; off <<= 1) {
    int x = (t >= off) ? ts[t - off] : 0;
    __syncthreads();
    ts[t] += x;
    __syncthreads();
  }
  int excl = (t == 0) ? 0 : ts[t - 1];
#pragma unroll
  for (int i = 0; i < 4; ++i) {
    int idx = base + i;
    if (idx < N) { row_ptr[idx] = excl; excl += v[i]; }
  }
  if (t == 255) bsum[blockIdx.x] = ts[255];
}

// Stage B: one block scans the block sums (nb <= 256) -> exclusive, total at bsum[nb].
__global__ __launch_bounds__(256) void k_scan_bsum(int* __restrict__ bsum, int nb) {
  __shared__ int sm[256];
  int t = threadIdx.x;
  sm[t] = (t < nb) ? bsum[t] : 0;
  __syncthreads();
#pragma unroll
  for (int off = 1; off < 256; off <<= 1) {
    int x = (t >= off) ? sm[t - off] : 0;
    __syncthreads();
    sm[t] += x;
    __syncthreads();
  }
  if (t < nb) bsum[t] = (t == 0) ? 0 : sm[t - 1];
  if (t == 255) bsum[nb] = sm[255];  // grand total
}

// Stage C merged with cursor/self-loop init: finalize row_ptr, plant self-loop,
// set cursor past it.
__global__ __launch_bounds__(256) void k_scan_add_cursor(int* __restrict__ row_ptr,
                                                         const int* __restrict__ bsum,
                                                         int* __restrict__ cursor,
                                                         int* __restrict__ ssrc,
                                                         int N, int nb) {
  int i = blockIdx.x * 256 + threadIdx.x;
  if (i < N) {
    int p = row_ptr[i] + bsum[i / SCAN_B];
    row_ptr[i] = p;
    ssrc[p] = i;          // self-loop edge first in segment
    cursor[i] = p + 1;
  }
  if (i == N) row_ptr[N] = bsum[nb];
}

// dst-range partitioned scatter: chunk's cursor + ssrc window stay L2-resident
// on one XCD -> writes coalesce into full lines.
__global__ __launch_bounds__(256) void k_scatter(const int* __restrict__ src,
                                                 const int* __restrict__ dst,
                                                 int* __restrict__ cursor,
                                                 int* __restrict__ ssrc, int E, int N) {
  int c = blockIdx.x & (NCHUNK - 1);
  int b0 = (c * N) / NCHUNK, b1 = ((c + 1) * N) / NCHUNK;
  int stride = (gridDim.x / NCHUNK) * 256;
  for (int e = (blockIdx.x >> 3) * 256 + threadIdx.x; e < E; e += stride) {
    int d = dst[e];
    if (d >= b0 && d < b1) {
      int p = atomicAdd(&cursor[d], 1);
      ssrc[p] = src[e];
    }
  }
}

// ---------------- encoder: h = relu(x @ W_enc + b_enc), tiled ----------------

__global__ __launch_bounds__(256) void k_encoder(const float* __restrict__ x,
                                                 const float* __restrict__ W,
                                                 const float* __restrict__ b,
                                                 float* __restrict__ h, int N) {
  __shared__ float xT[F][64];   // 32 KiB, k-major
  __shared__ float Ws[F][64];   // 32 KiB, [k][c]
  int t = threadIdx.x;
  int n0 = blockIdx.x * 64;
  for (int i = t; i < F * D / 4; i += 256)
    ((float4*)&Ws[0][0])[i] = ((const float4*)W)[i];
  {
    int r = t & 63, kq = (t >> 6) * 4;
    int n = n0 + r;
#pragma unroll
    for (int i = 0; i < 8; ++i) {
      int k0 = kq + 16 * i;
      float4 v = (n < N) ? *(const float4*)&x[(size_t)n * F + k0]
                         : make_float4(0.f, 0.f, 0.f, 0.f);
      xT[k0][r] = v.x; xT[k0 + 1][r] = v.y; xT[k0 + 2][r] = v.z; xT[k0 + 3][r] = v.w;
    }
  }
  __syncthreads();
  int c4 = (t & 15) * 4, n4 = (t >> 4) * 4;
  float acc[4][4];
#pragma unroll
  for (int i = 0; i < 4; ++i)
#pragma unroll
    for (int j = 0; j < 4; ++j) acc[i][j] = b[c4 + j];
#pragma unroll 4
  for (int k = 0; k < F; ++k) {
    float4 xv = *(const float4*)&xT[k][n4];
    float4 wv = *(const float4*)&Ws[k][c4];
    const float* xp = (const float*)&xv;
    const float* wp = (const float*)&wv;
#pragma unroll
    for (int i = 0; i < 4; ++i)
#pragma unroll
      for (int j = 0; j < 4; ++j) acc[i][j] = fmaf(xp[i], wp[j], acc[i][j]);
  }
#pragma unroll
  for (int i = 0; i < 4; ++i) {
    int n = n0 + n4 + i;
    if (n < N) {
      float4 o = make_float4(fmaxf(acc[i][0], 0.f), fmaxf(acc[i][1], 0.f),
                             fmaxf(acc[i][2], 0.f), fmaxf(acc[i][3], 0.f));
      *(float4*)&h[(size_t)n * D + c4] = o;
    }
  }
}

// ---------------- per-layer projections: xl = h@Wl+bl, xr = h@Wr+br, tiled ----------------

__global__ __launch_bounds__(256) void k_layer_gemm(const float* __restrict__ h,
                                                    const float* __restrict__ Wl,
                                                    const float* __restrict__ bl,
                                                    const float* __restrict__ Wr,
                                                    const float* __restrict__ br,
                                                    float* __restrict__ xl,
                                                    float* __restrict__ xr, int N) {
  __shared__ float hT[D][64];    // 16 KiB, k-major
  __shared__ float Wls[D][64];   // 16 KiB
  __shared__ float Wrs[D][64];   // 16 KiB
  int t = threadIdx.x;
  int n0 = blockIdx.x * 64;
  for (int i = t; i < D * D / 4; i += 256) {
    ((float4*)&Wls[0][0])[i] = ((const float4*)Wl)[i];
    ((float4*)&Wrs[0][0])[i] = ((const float4*)Wr)[i];
  }
  {
    int r = t & 63, kq = (t >> 6) * 4;
    int n = n0 + r;
#pragma unroll
    for (int i = 0; i < 4; ++i) {
      int k0 = kq + 16 * i;
      float4 v = (n < N) ? *(const float4*)&h[(size_t)n * D + k0]
                         : make_float4(0.f, 0.f, 0.f, 0.f);
      hT[k0][r] = v.x; hT[k0 + 1][r] = v.y; hT[k0 + 2][r] = v.z; hT[k0 + 3][r] = v.w;
    }
  }
  __syncthreads();
  int c4 = (t & 15) * 4, n4 = (t >> 4) * 4;
  float aL[4][4], aR[4][4];
#pragma unroll
  for (int i = 0; i < 4; ++i)
#pragma unroll
    for (int j = 0; j < 4; ++j) { aL[i][j] = bl[c4 + j]; aR[i][j] = br[c4 + j]; }
#pragma unroll 4
  for (int k = 0; k < D; ++k) {
    float4 xv = *(const float4*)&hT[k][n4];
    float4 lv = *(const float4*)&Wls[k][c4];
    float4 rv = *(const float4*)&Wrs[k][c4];
    const float* xp = (const float*)&xv;
    const float* lp = (const float*)&lv;
    const float* rp = (const float*)&rv;
#pragma unroll
    for (int i = 0; i < 4; ++i)
#pragma unroll
      for (int j = 0; j < 4; ++j) {
        aL[i][j] = fmaf(xp[i], lp[j], aL[i][j]);
        aR[i][j] = fmaf(xp[i], rp[j], aR[i][j]);
      }
  }
#pragma unroll
  for (int i = 0; i < 4; ++i) {
    int n = n0 + n4 + i;
    if (n < N) {
      *(float4*)&xl[(size_t)n * D + c4] =
          make_float4(aL[i][0], aL[i][1], aL[i][2], aL[i][3]);
      *(float4*)&xr[(size_t)n * D + c4] =
          make_float4(aR[i][0], aR[i][1], aR[i][2], aR[i][3]);
    }
  }
}

// ---------------- edge + softmax + aggregate + LN + ELU ----------------
// One wave per dst node, node-level software pipeline: next node's
// row_ptr/xr/ssrc/first-16 gathers are issued before the current node's
// LN epilogue, hiding the serial load chain at every node start.
// R6-style fused-FMA accumulator chains (tree only for pmax: op-neutral).

template <int B, bool MASK>
__device__ __forceinline__ void gather_idx(const int* __restrict__ ssrc, int e,
                                           int cnt, int sj[B]) {
#pragma unroll
  for (int g = 0; g < B / 4; ++g) {
    // same-address 16B load (broadcast), then force components into SGPRs
    int4 q = *(const int4*)(ssrc + e + 4 * g);
    sj[4 * g + 0] = __builtin_amdgcn_readfirstlane(q.x);
    sj[4 * g + 1] = __builtin_amdgcn_readfirstlane(q.y);
    sj[4 * g + 2] = __builtin_amdgcn_readfirstlane(q.z);
    sj[4 * g + 3] = __builtin_amdgcn_readfirstlane(q.w);
  }
  if (MASK) {
#pragma unroll
    for (int j = 1; j < B; ++j)
      if (j >= cnt) sj[j] = sj[0];   // duplicate gather -> L1 hit, score masked
  }
}

template <int B>
__device__ __forceinline__ void gather_xs(const float* __restrict__ xl,
                                          const int sj[B], int lane, float xs[B]) {
#pragma unroll
  for (int j = 0; j < B; ++j) xs[j] = xl[(size_t)sj[j] * D + lane];
}

template <int B, bool MASK>
__device__ __forceinline__ void process_batch(const float xs[B], int cnt, float xr_j,
                                              float a, int lane,
                                              float& m, float& s, float& acc) {
  float p[B];
#pragma unroll
  for (int j = 0; j < B; ++j) {
    float v = xs[j] + xr_j;
    float lr = fmaxf(v, NEG_SLOPE * v);   // exact for 0<slope<1
    float pj = red16(a * lr);             // per-head score (log2 domain)
    if (MASK && j >= cnt) pj = -INFINITY;
    p[j] = pj;
  }
  // tree max (same op count as serial, 4x less depth)
  float pm[B];
#pragma unroll
  for (int j = 0; j < B; ++j) pm[j] = p[j];
#pragma unroll
  for (int off = B / 2; off > 0; off >>= 1)
#pragma unroll
    for (int j = 0; j < off; ++j) pm[j] = fmaxf(pm[j], pm[j + off]);
  float mnew = fmaxf(m, pm[0]);
  float c = __builtin_amdgcn_exp2f(m - mnew);   // first batch: 2^(-inf)=0
  // two interleaved fused-FMA chains (R6 form, halved depth)
  float s0 = 0.f, s1 = 0.f, a0 = 0.f, a1 = 0.f;
#pragma unroll
  for (int j = 0; j < B; j += 2) {
    float w0 = __builtin_amdgcn_exp2f(p[j] - mnew);
    float w1 = __builtin_amdgcn_exp2f(p[j + 1] - mnew);
    s0 += w0; a0 = fmaf(w0, xs[j], a0);
    s1 += w1; a1 = fmaf(w1, xs[j + 1], a1);
  }
  s = fmaf(s, c, s0 + s1);
  acc = fmaf(acc, c, a0 + a1);
  m = mnew;
}

__global__ __launch_bounds__(256) void k_edge_layer(const float* __restrict__ xl,
                                                    const float* __restrict__ xr,
                                                    const int* __restrict__ row_ptr,
                                                    const int* __restrict__ ssrc,
                                                    const float* __restrict__ att_l,
                                                    const float* __restrict__ ob_l,
                                                    const float* __restrict__ g_l,
                                                    const float* __restrict__ be_l,
                                                    float* __restrict__ out, int N) {
  int lane = threadIdx.x & 63;
  int wid = threadIdx.x >> 6;
  int wave = blockIdx.x * 4 + wid;
  int nw = gridDim.x * 4;
  float a = att_l[lane] * LOG2E;   // exp2 domain: softmax ratios exactly invariant
  float ob = ob_l[lane], gam = g_l[lane], bet = be_l[lane];

  int i = wave;
  if (i >= N) return;
  // prologue prefetch: node i context + first-16 gather
  int e0 = __builtin_amdgcn_readfirstlane(row_ptr[i]);
  int e1 = __builtin_amdgcn_readfirstlane(row_ptr[i + 1]);
  float xr_j = xr[(size_t)i * D + lane];
  float xsA[16];
  {
    int sj[16];
    gather_idx<16, true>(ssrc, e0, min(e1 - e0, 16), sj);
    gather_xs<16>(xl, sj, lane, xsA);
  }
  while (true) {
    int ce0 = e0, ce1 = e1;
    float cxr = xr_j;
    float m = -INFINITY, s = 0.f, acc = 0.f;
    // first batch (prefetched); wave-uniform branch picks unmasked variant
    int cnt1 = ce1 - ce0;
    if (cnt1 >= 16)
      process_batch<16, false>(xsA, 16, cxr, a, lane, m, s, acc);
    else
      process_batch<16, true>(xsA, cnt1, cxr, a, lane, m, s, acc);
    int e = ce0 + 16;
    // remainder batches (deg > 16 only)
    while (e + 8 <= ce1) {
      int sj[8]; float xs[8];
      gather_idx<8, false>(ssrc, e, 8, sj);
      gather_xs<8>(xl, sj, lane, xs);
      process_batch<8, false>(xs, 8, cxr, a, lane, m, s, acc);
      e += 8;
    }
    if (e + 4 <= ce1) {
      int sj[4]; float xs[4];
      gather_idx<4, false>(ssrc, e, 4, sj);
      gather_xs<4>(xl, sj, lane, xs);
      process_batch<4, false>(xs, 4, cxr, a, lane, m, s, acc);
      e += 4;
    }
    if (e < ce1) {
      int sj[4]; float xs[4];
      gather_idx<4, true>(ssrc, e, ce1 - e, sj);
      gather_xs<4>(xl, sj, lane, xs);
      process_batch<4, true>(xs, ce1 - e, cxr, a, lane, m, s, acc);
    }
    // prefetch NEXT node before the epilogue (loads overlap LN math)
    int inext = i + nw;
    bool more = inext < N;
    if (more) {
      e0 = __builtin_amdgcn_readfirstlane(row_ptr[inext]);
      e1 = __builtin_amdgcn_readfirstlane(row_ptr[inext + 1]);
      xr_j = xr[(size_t)inext * D + lane];
      int sj[16];
      gather_idx<16, true>(ssrc, e0, min(e1 - e0, 16), sj);
      gather_xs<16>(xl, sj, lane, xsA);
    }
    // epilogue: softmax finalize + LayerNorm + ELU + store (covers prefetch)
    float res = fmaf(acc, __builtin_amdgcn_rcpf(s), ob);
    float mu = red64(res) * (1.f / 64.f);
    float dv = res - mu;
    float var = red64(dv * dv) * (1.f / 64.f);
    float hn = dv * rsqrtf(var + LN_EPS) * gam + bet;
    out[(size_t)i * D + lane] = hn > 0.f ? hn : expm1f(hn);
    if (!more) break;
    i = inext;
  }
}

// ---------------- launch ----------------

extern "C" void kernel_launch(void* const* d_in, const int* in_sizes, int n_in,
                              void* d_out, int out_size, void* d_ws, size_t ws_size,
                              hipStream_t stream) {
  const float* x      = (const float*)d_in[0];
  const int*   ei     = (const int*)d_in[1];
  const float* W_enc  = (const float*)d_in[2];
  const float* b_enc  = (const float*)d_in[3];
  const float* Wl     = (const float*)d_in[4];
  const float* bl     = (const float*)d_in[5];
  const float* Wr     = (const float*)d_in[6];
  const float* br     = (const float*)d_in[7];
  const float* att    = (const float*)d_in[8];
  const float* obias  = (const float*)d_in[9];
  const float* gamma  = (const float*)d_in[10];
  const float* beta   = (const float*)d_in[11];

  int N = in_sizes[0] / F;       // 100000
  int E = in_sizes[1] / 2;       // 1600000
  const int* src = ei;
  const int* dst = ei + E;

  auto align = [](size_t v) { return (v + 255) & ~(size_t)255; };
  char* ws = (char*)d_ws;
  float* h  = (float*)ws;  ws += align((size_t)N * D * 4);
  float* xl = (float*)ws;  ws += align((size_t)N * D * 4);
  float* xr = (float*)ws;  ws += align((size_t)N * D * 4);
  int* row_ptr = (int*)ws; ws += align((size_t)(N + 1) * 4);
  int* cursor  = (int*)ws; ws += align((size_t)N * 4);       // also used as cnt
  int* ssrc    = (int*)ws; ws += align((size_t)(N + E) * 4);
  int* bsum    = (int*)ws; ws += align((size_t)1024 * 4);    // also tail-read pad for ssrc

  int nblk = (N + 255) / 256;
  int tblk = (N + 63) / 64;
  int nb = (N + SCAN_B - 1) / SCAN_B;   // 98 for N=100000 (must be <= 256)

  // CSR build (counting sort by dst; self-loop first in each segment)
  k_init_cnt<<<nblk, 256, 0, stream>>>(cursor, N);
  k_hist<<<2048, 256, 0, stream>>>(dst, cursor, E, N);
  k_scan_local<<<nb, 256, 0, stream>>>(cursor, row_ptr, bsum, N);
  k_scan_bsum<<<1, 256, 0, stream>>>(bsum, nb);
  k_scan_add_cursor<<<(N + 256) / 256, 256, 0, stream>>>(row_ptr, bsum, cursor, ssrc, N, nb);
  k_scatter<<<2048, 256, 0, stream>>>(src, dst, cursor, ssrc, E, N);

  // encoder
  k_encoder<<<tblk, 256, 0, stream>>>(x, W_enc, b_enc, h, N);

  for (int l = 0; l < 3; ++l) {
    k_layer_gemm<<<tblk, 256, 0, stream>>>(h, Wl + l * D * D, bl + l * D,
                                           Wr + l * D * D, br + l * D, xl, xr, N);
    float* out = (l == 2) ? (float*)d_out : h;
    k_edge_layer<<<2048, 256, 0, stream>>>(xl, xr, row_ptr, ssrc, att + l * 64,
                                           obias + l * 64, gamma + l * 64,
                                           beta + l * 64, out, N);
  }
}

// Round 10
// 492.331 us; speedup vs baseline: 1.0912x; 1.0912x over previous
//
#include <hip/hip_runtime.h>
#include <hip/hip_fp16.h>
#include <math.h>

static constexpr int D = 64;     // hidden dim
static constexpr int F = 128;    // input features
static constexpr float NEG_SLOPE = 0.2f;
static constexpr float LN_EPS = 1e-5f;
static constexpr float LOG2E = 1.44269504088896340736f;
static constexpr int SCAN_B = 1024;  // elements per scan block (256 thr x 4)
static constexpr int EB = 16;        // edge batch
static constexpr int NCHUNK = 8;     // dst-range chunks (== NXCD)

// ---- DPP cross-lane reduction helpers (no LDS traffic) ----
template <int CTRL>
__device__ __forceinline__ float dpp_add(float x) {
  int v = __builtin_amdgcn_update_dpp(0, __float_as_int(x), CTRL, 0xF, 0xF, true);
  return x + __int_as_float(v);
}
// sum within each aligned 16-lane group (result replicated in all 16 lanes)
__device__ __forceinline__ float red16(float x) {
  x = dpp_add<0xB1>(x);    // quad_perm [1,0,3,2]  (xor 1)
  x = dpp_add<0x4E>(x);    // quad_perm [2,3,0,1]  (xor 2)
  x = dpp_add<0x141>(x);   // row_half_mirror
  x = dpp_add<0x140>(x);   // row_mirror
  return x;
}
// sum across full 64-lane wave
__device__ __forceinline__ float red64(float x) {
  x = red16(x);
  x += __shfl_xor(x, 16);
  x += __shfl_xor(x, 32);
  return x;
}

// ---------------- CSR build ----------------

__global__ __launch_bounds__(256) void k_init_cnt(int* __restrict__ cnt, int N) {
  int i = blockIdx.x * 256 + threadIdx.x;
  if (i < N) cnt[i] = 1;  // self-loop
}

// dst-range partitioned histogram: chunk c = blockIdx%8 -> XCD-local atomics.
__global__ __launch_bounds__(256) void k_hist(const int* __restrict__ dst,
                                              int* __restrict__ cnt, int E, int N) {
  int c = blockIdx.x & (NCHUNK - 1);
  int b0 = (c * N) / NCHUNK, b1 = ((c + 1) * N) / NCHUNK;
  int stride = (gridDim.x / NCHUNK) * 256;
  for (int e = (blockIdx.x >> 3) * 256 + threadIdx.x; e < E; e += stride) {
    int d = dst[e];
    if (d >= b0 && d < b1) atomicAdd(&cnt[d], 1);
  }
}

// Stage A: per-block local exclusive scan (4 elems/thread) + block sum.
__global__ __launch_bounds__(256) void k_scan_local(const int* __restrict__ cnt,
                                                    int* __restrict__ row_ptr,
                                                    int* __restrict__ bsum, int N) {
  __shared__ int ts[256];
  int t = threadIdx.x;
  int base = blockIdx.x * SCAN_B + t * 4;
  int v[4];
  int s = 0;
#pragma unroll
  for (int i = 0; i < 4; ++i) {
    int idx = base + i;
    v[i] = (idx < N) ? cnt[idx] : 0;
    s += v[i];
  }
  ts[t] = s;
  __syncthreads();
#pragma unroll
  for (int off = 1; off < 256; off <<= 1) {
    int x = (t >= off) ? ts[t - off] : 0;
    __syncthreads();
    ts[t] += x;
    __syncthreads();
  }
  int excl = (t == 0) ? 0 : ts[t - 1];
#pragma unroll
  for (int i = 0; i < 4; ++i) {
    int idx = base + i;
    if (idx < N) { row_ptr[idx] = excl; excl += v[i]; }
  }
  if (t == 255) bsum[blockIdx.x] = ts[255];
}

// Stage B: one block scans the block sums (nb <= 256) -> exclusive, total at bsum[nb].
__global__ __launch_bounds__(256) void k_scan_bsum(int* __restrict__ bsum, int nb) {
  __shared__ int sm[256];
  int t = threadIdx.x;
  sm[t] = (t < nb) ? bsum[t] : 0;
  __syncthreads();
#pragma unroll
  for (int off = 1; off < 256; off <<= 1) {
    int x = (t >= off) ? sm[t - off] : 0;
    __syncthreads();
    sm[t] += x;
    __syncthreads();
  }
  if (t < nb) bsum[t] = (t == 0) ? 0 : sm[t - 1];
  if (t == 255) bsum[nb] = sm[255];  // grand total
}

// Stage C merged with cursor/self-loop init: finalize row_ptr, plant self-loop,
// set cursor past it.
__global__ __launch_bounds__(256) void k_scan_add_cursor(int* __restrict__ row_ptr,
                                                         const int* __restrict__ bsum,
                                                         int* __restrict__ cursor,
                                                         int* __restrict__ ssrc,
                                                         int N, int nb) {
  int i = blockIdx.x * 256 + threadIdx.x;
  if (i < N) {
    int p = row_ptr[i] + bsum[i / SCAN_B];
    row_ptr[i] = p;
    ssrc[p] = i;          // self-loop edge first in segment
    cursor[i] = p + 1;
  }
  if (i == N) row_ptr[N] = bsum[nb];
}

// dst-range partitioned scatter: chunk's cursor + ssrc window stay L2-resident
// on one XCD -> writes coalesce into full lines.
__global__ __launch_bounds__(256) void k_scatter(const int* __restrict__ src,
                                                 const int* __restrict__ dst,
                                                 int* __restrict__ cursor,
                                                 int* __restrict__ ssrc, int E, int N) {
  int c = blockIdx.x & (NCHUNK - 1);
  int b0 = (c * N) / NCHUNK, b1 = ((c + 1) * N) / NCHUNK;
  int stride = (gridDim.x / NCHUNK) * 256;
  for (int e = (blockIdx.x >> 3) * 256 + threadIdx.x; e < E; e += stride) {
    int d = dst[e];
    if (d >= b0 && d < b1) {
      int p = atomicAdd(&cursor[d], 1);
      ssrc[p] = src[e];
    }
  }
}

// ---------------- encoder: h = relu(x @ W_enc + b_enc), tiled ----------------

__global__ __launch_bounds__(256) void k_encoder(const float* __restrict__ x,
                                                 const float* __restrict__ W,
                                                 const float* __restrict__ b,
                                                 float* __restrict__ h, int N) {
  __shared__ float xT[F][64];   // 32 KiB, k-major
  __shared__ float Ws[F][64];   // 32 KiB, [k][c]
  int t = threadIdx.x;
  int n0 = blockIdx.x * 64;
  for (int i = t; i < F * D / 4; i += 256)
    ((float4*)&Ws[0][0])[i] = ((const float4*)W)[i];
  {
    int r = t & 63, kq = (t >> 6) * 4;
    int n = n0 + r;
#pragma unroll
    for (int i = 0; i < 8; ++i) {
      int k0 = kq + 16 * i;
      float4 v = (n < N) ? *(const float4*)&x[(size_t)n * F + k0]
                         : make_float4(0.f, 0.f, 0.f, 0.f);
      xT[k0][r] = v.x; xT[k0 + 1][r] = v.y; xT[k0 + 2][r] = v.z; xT[k0 + 3][r] = v.w;
    }
  }
  __syncthreads();
  int c4 = (t & 15) * 4, n4 = (t >> 4) * 4;
  float acc[4][4];
#pragma unroll
  for (int i = 0; i < 4; ++i)
#pragma unroll
    for (int j = 0; j < 4; ++j) acc[i][j] = b[c4 + j];
#pragma unroll 4
  for (int k = 0; k < F; ++k) {
    float4 xv = *(const float4*)&xT[k][n4];
    float4 wv = *(const float4*)&Ws[k][c4];
    const float* xp = (const float*)&xv;
    const float* wp = (const float*)&wv;
#pragma unroll
    for (int i = 0; i < 4; ++i)
#pragma unroll
      for (int j = 0; j < 4; ++j) acc[i][j] = fmaf(xp[i], wp[j], acc[i][j]);
  }
#pragma unroll
  for (int i = 0; i < 4; ++i) {
    int n = n0 + n4 + i;
    if (n < N) {
      float4 o = make_float4(fmaxf(acc[i][0], 0.f), fmaxf(acc[i][1], 0.f),
                             fmaxf(acc[i][2], 0.f), fmaxf(acc[i][3], 0.f));
      *(float4*)&h[(size_t)n * D + c4] = o;
    }
  }
}

// ---------------- per-layer projections: xl(fp16) = h@Wl+bl, xr(f32) = h@Wr+br ----------------

__global__ __launch_bounds__(256) void k_layer_gemm(const float* __restrict__ h,
                                                    const float* __restrict__ Wl,
                                                    const float* __restrict__ bl,
                                                    const float* __restrict__ Wr,
                                                    const float* __restrict__ br,
                                                    ushort* __restrict__ xlh,
                                                    float* __restrict__ xr, int N) {
  __shared__ float hT[D][64];    // 16 KiB, k-major
  __shared__ float Wls[D][64];   // 16 KiB
  __shared__ float Wrs[D][64];   // 16 KiB
  int t = threadIdx.x;
  int n0 = blockIdx.x * 64;
  for (int i = t; i < D * D / 4; i += 256) {
    ((float4*)&Wls[0][0])[i] = ((const float4*)Wl)[i];
    ((float4*)&Wrs[0][0])[i] = ((const float4*)Wr)[i];
  }
  {
    int r = t & 63, kq = (t >> 6) * 4;
    int n = n0 + r;
#pragma unroll
    for (int i = 0; i < 4; ++i) {
      int k0 = kq + 16 * i;
      float4 v = (n < N) ? *(const float4*)&h[(size_t)n * D + k0]
                         : make_float4(0.f, 0.f, 0.f, 0.f);
      hT[k0][r] = v.x; hT[k0 + 1][r] = v.y; hT[k0 + 2][r] = v.z; hT[k0 + 3][r] = v.w;
    }
  }
  __syncthreads();
  int c4 = (t & 15) * 4, n4 = (t >> 4) * 4;
  float aL[4][4], aR[4][4];
#pragma unroll
  for (int i = 0; i < 4; ++i)
#pragma unroll
    for (int j = 0; j < 4; ++j) { aL[i][j] = bl[c4 + j]; aR[i][j] = br[c4 + j]; }
#pragma unroll 4
  for (int k = 0; k < D; ++k) {
    float4 xv = *(const float4*)&hT[k][n4];
    float4 lv = *(const float4*)&Wls[k][c4];
    float4 rv = *(const float4*)&Wrs[k][c4];
    const float* xp = (const float*)&xv;
    const float* lp = (const float*)&lv;
    const float* rp = (const float*)&rv;
#pragma unroll
    for (int i = 0; i < 4; ++i)
#pragma unroll
      for (int j = 0; j < 4; ++j) {
        aL[i][j] = fmaf(xp[i], lp[j], aL[i][j]);
        aR[i][j] = fmaf(xp[i], rp[j], aR[i][j]);
      }
  }
#pragma unroll
  for (int i = 0; i < 4; ++i) {
    int n = n0 + n4 + i;
    if (n < N) {
      ushort4 o;
      o.x = __half_as_ushort(__float2half_rn(aL[i][0]));
      o.y = __half_as_ushort(__float2half_rn(aL[i][1]));
      o.z = __half_as_ushort(__float2half_rn(aL[i][2]));
      o.w = __half_as_ushort(__float2half_rn(aL[i][3]));
      *(ushort4*)&xlh[(size_t)n * D + c4] = o;
      *(float4*)&xr[(size_t)n * D + c4] =
          make_float4(aR[i][0], aR[i][1], aR[i][2], aR[i][3]);
    }
  }
}

// ---------------- edge + softmax + aggregate + LN + ELU ----------------
// One wave per dst node (R6 structure, proven best). Edge indices are
// wave-uniform -> SGPRs via readfirstlane. Hierarchical batches 16/4/masked-4.
// xl gathered as fp16 (halves the dominant random-row fill traffic).

template <int B, bool MASK>
__device__ __forceinline__ void edge_batch(const ushort* __restrict__ xlh,
                                           const int* __restrict__ ssrc,
                                           int e, int cnt, float xr_j, float a,
                                           int lane, float& m, float& s, float& acc) {
  int sj[B];
#pragma unroll
  for (int g = 0; g < B / 4; ++g) {
    // same-address 16B load (broadcast), then force components into SGPRs
    int4 q = *(const int4*)(ssrc + e + 4 * g);
    sj[4 * g + 0] = __builtin_amdgcn_readfirstlane(q.x);
    sj[4 * g + 1] = __builtin_amdgcn_readfirstlane(q.y);
    sj[4 * g + 2] = __builtin_amdgcn_readfirstlane(q.z);
    sj[4 * g + 3] = __builtin_amdgcn_readfirstlane(q.w);
  }
  if (MASK) {
#pragma unroll
    for (int j = 1; j < B; ++j)
      if (j >= cnt) sj[j] = sj[0];   // duplicate gather -> L1 hit, score masked
  }
  float xs[B], p[B];
#pragma unroll
  for (int j = 0; j < B; ++j)
    xs[j] = __half2float(__ushort_as_half(xlh[(size_t)sj[j] * D + lane]));
#pragma unroll
  for (int j = 0; j < B; ++j) {
    float v = xs[j] + xr_j;
    float lr = fmaxf(v, NEG_SLOPE * v);   // exact for 0<slope<1
    float pj = red16(a * lr);             // per-head score (log2 domain)
    if (MASK && j >= cnt) pj = -INFINITY;
    p[j] = pj;
  }
  float pmax = p[0];
#pragma unroll
  for (int j = 1; j < B; ++j) pmax = fmaxf(pmax, p[j]);
  float mnew = fmaxf(m, pmax);
  float c = __builtin_amdgcn_exp2f(m - mnew);   // first batch: 2^(-inf)=0
  s *= c; acc *= c;
#pragma unroll
  for (int j = 0; j < B; ++j) {
    float w = __builtin_amdgcn_exp2f(p[j] - mnew);
    s += w;
    acc = fmaf(w, xs[j], acc);
  }
  m = mnew;
}

__global__ __launch_bounds__(256) void k_edge_layer(const ushort* __restrict__ xlh,
                                                    const float* __restrict__ xr,
                                                    const int* __restrict__ row_ptr,
                                                    const int* __restrict__ ssrc,
                                                    const float* __restrict__ att_l,
                                                    const float* __restrict__ ob_l,
                                                    const float* __restrict__ g_l,
                                                    const float* __restrict__ be_l,
                                                    float* __restrict__ out, int N) {
  int lane = threadIdx.x & 63;
  int wid = threadIdx.x >> 6;
  int wave = blockIdx.x * 4 + wid;
  int nw = gridDim.x * 4;
  float a = att_l[lane] * LOG2E;   // exp2 domain: softmax ratios exactly invariant
  float ob = ob_l[lane], gam = g_l[lane], bet = be_l[lane];
  for (int i = wave; i < N; i += nw) {
    float xr_j = xr[(size_t)i * D + lane];
    int e0 = __builtin_amdgcn_readfirstlane(row_ptr[i]);
    int e1 = __builtin_amdgcn_readfirstlane(row_ptr[i + 1]);
    float m = -INFINITY, s = 0.f, acc = 0.f;
    int e = e0;
    for (; e + 16 <= e1; e += 16)
      edge_batch<16, false>(xlh, ssrc, e, 16, xr_j, a, lane, m, s, acc);
    for (; e + 4 <= e1; e += 4)
      edge_batch<4, false>(xlh, ssrc, e, 4, xr_j, a, lane, m, s, acc);
    if (e < e1)
      edge_batch<4, true>(xlh, ssrc, e, e1 - e, xr_j, a, lane, m, s, acc);
    float res = fmaf(acc, __builtin_amdgcn_rcpf(s), ob);
    // LayerNorm across the 64 channels (full wave)
    float mu = red64(res) * (1.f / 64.f);
    float dv = res - mu;
    float var = red64(dv * dv) * (1.f / 64.f);
    float hn = dv * rsqrtf(var + LN_EPS) * gam + bet;
    out[(size_t)i * D + lane] = hn > 0.f ? hn : expm1f(hn);
  }
}

// ---------------- launch ----------------

extern "C" void kernel_launch(void* const* d_in, const int* in_sizes, int n_in,
                              void* d_out, int out_size, void* d_ws, size_t ws_size,
                              hipStream_t stream) {
  const float* x      = (const float*)d_in[0];
  const int*   ei     = (const int*)d_in[1];
  const float* W_enc  = (const float*)d_in[2];
  const float* b_enc  = (const float*)d_in[3];
  const float* Wl     = (const float*)d_in[4];
  const float* bl     = (const float*)d_in[5];
  const float* Wr     = (const float*)d_in[6];
  const float* br     = (const float*)d_in[7];
  const float* att    = (const float*)d_in[8];
  const float* obias  = (const float*)d_in[9];
  const float* gamma  = (const float*)d_in[10];
  const float* beta   = (const float*)d_in[11];

  int N = in_sizes[0] / F;       // 100000
  int E = in_sizes[1] / 2;       // 1600000
  const int* src = ei;
  const int* dst = ei + E;

  auto align = [](size_t v) { return (v + 255) & ~(size_t)255; };
  char* ws = (char*)d_ws;
  float* h  = (float*)ws;   ws += align((size_t)N * D * 4);
  ushort* xlh = (ushort*)ws; ws += align((size_t)N * D * 2);
  float* xr = (float*)ws;   ws += align((size_t)N * D * 4);
  int* row_ptr = (int*)ws;  ws += align((size_t)(N + 1) * 4);
  int* cursor  = (int*)ws;  ws += align((size_t)N * 4);       // also used as cnt
  int* ssrc    = (int*)ws;  ws += align((size_t)(N + E) * 4);
  int* bsum    = (int*)ws;  ws += align((size_t)1024 * 4);    // also tail-read pad for ssrc

  int nblk = (N + 255) / 256;
  int tblk = (N + 63) / 64;
  int nb = (N + SCAN_B - 1) / SCAN_B;   // 98 for N=100000 (must be <= 256)

  // CSR build (counting sort by dst; self-loop first in each segment)
  k_init_cnt<<<nblk, 256, 0, stream>>>(cursor, N);
  k_hist<<<2048, 256, 0, stream>>>(dst, cursor, E, N);
  k_scan_local<<<nb, 256, 0, stream>>>(cursor, row_ptr, bsum, N);
  k_scan_bsum<<<1, 256, 0, stream>>>(bsum, nb);
  k_scan_add_cursor<<<(N + 256) / 256, 256, 0, stream>>>(row_ptr, bsum, cursor, ssrc, N, nb);
  k_scatter<<<2048, 256, 0, stream>>>(src, dst, cursor, ssrc, E, N);

  // encoder
  k_encoder<<<tblk, 256, 0, stream>>>(x, W_enc, b_enc, h, N);

  for (int l = 0; l < 3; ++l) {
    k_layer_gemm<<<tblk, 256, 0, stream>>>(h, Wl + l * D * D, bl + l * D,
                                           Wr + l * D * D, br + l * D, xlh, xr, N);
    float* out = (l == 2) ? (float*)d_out : h;
    k_edge_layer<<<2048, 256, 0, stream>>>(xlh, xr, row_ptr, ssrc, att + l * 64,
                                           obias + l * 64, gamma + l * 64,
                                           beta + l * 64, out, N);
  }
}